// Round 7
// baseline (98.492 us; speedup 1.0000x reference)
//
#include <hip/hip_runtime.h>
#include <hip/hip_bf16.h>

// y = x @ (W^T * S), S = sum_{k=0}^{100} (-M)^k ~= prod_{i=0}^{4} (I + A^(2^i)), A = -M.
// Chain: 5 k-parallel launches; last writes P in K-MAJOR bf16 layout Ptk[kt][col][32]
// (so GEMM B-loads are fully line-contiguous). GEMM: x staged ONCE per block as full
// contiguous 2KB rows (xs[64][512] f32, 128 KB LDS) -> barrier-free k-loop; B direct
// from global (L2-resident) with depth-2 register prefetch. Every VMEM instruction
// covers contiguous full 128B lines (the round-1..6 kernels were sector-transaction
// bound on scattered staging patterns).

typedef float f32x4 __attribute__((ext_vector_type(4)));
typedef __bf16 bf16x8 __attribute__((ext_vector_type(8)));

#define IN 512
#define OUT 256
#define BATCH 65536

#define GLOAD_LDS16(gp, lp)                                                              \
    __builtin_amdgcn_global_load_lds((const __attribute__((address_space(1))) void*)(gp), \
                                     (__attribute__((address_space(3))) void*)(lp), 16, 0, 0)

// ---------------- chain: k-parallel small matmuls (verified rounds 1-6) ----------------
__device__ __forceinline__ void chain_core(const float (*sA)[256], const float* __restrict__ B,
                                           int j, int q, float acc[8]) {
#pragma unroll
    for (int r = 0; r < 8; ++r) acc[r] = 0.f;
    const int kbase = q * 64;
#pragma unroll
    for (int it = 0; it < 16; ++it) {
        const int k = kbase + it * 4;
        const float b0 = B[(k + 0) * 256 + j];
        const float b1 = B[(k + 1) * 256 + j];
        const float b2 = B[(k + 2) * 256 + j];
        const float b3 = B[(k + 3) * 256 + j];
#pragma unroll
        for (int r = 0; r < 8; ++r) {
            const f32x4 av = *(const f32x4*)&sA[r][k];
            acc[r] += av[0] * b0 + av[1] * b1 + av[2] * b2 + av[3] * b3;
        }
    }
}

__global__ __launch_bounds__(1024) void nsm_chain_step(const float* __restrict__ Bmat,
                                                       const float* __restrict__ Pin,
                                                       float* __restrict__ Tout,
                                                       float* __restrict__ Pout,
                                                       const int first) {
    __shared__ float sA[8][256];
    __shared__ float ws[4][8][256];
    const int t = threadIdx.x, j = t & 255, q = t >> 8, b = blockIdx.x;
    float acc[8];
    const bool isT = (b < 32);
    if (isT) {
        const int i0 = b * 8;
        sA[2 * q][j]     = Bmat[(i0 + 2 * q) * 256 + j];
        sA[2 * q + 1][j] = Bmat[(i0 + 2 * q + 1) * 256 + j];
    } else {
        const int i0 = (b - 32) * 8;
        if (first) {
            sA[2 * q][j]     = Pin[j * IN + i0 + 2 * q];
            sA[2 * q + 1][j] = Pin[j * IN + i0 + 2 * q + 1];
        } else {
            sA[2 * q][j]     = Pin[(i0 + 2 * q) * 256 + j];
            sA[2 * q + 1][j] = Pin[(i0 + 2 * q + 1) * 256 + j];
        }
    }
    __syncthreads();
    chain_core(sA, Bmat, j, q, acc);
#pragma unroll
    for (int r = 0; r < 8; ++r) ws[q][r][j] = acc[r];
    __syncthreads();
#pragma unroll
    for (int d = 0; d < 2; ++d) {
        const int r = 2 * q + d;
        const float v = ws[0][r][j] + ws[1][r][j] + ws[2][r][j] + ws[3][r][j];
        if (isT) {
            const int i0 = b * 8;
            Tout[(i0 + r) * 256 + j] = v;
        } else {
            const int i0 = (b - 32) * 8;
            Pout[(i0 + r) * 256 + j] = first ? (sA[r][j] - v) : (sA[r][j] + v);
        }
    }
}

// grid 64: P_final = Pin + Pin*Bmat, written K-MAJOR bf16: Ptk[kt][col][kk], kt=k>>5, kk=k&31.
// Transposed coalesced epilogue through sA.
__global__ __launch_bounds__(1024) void nsm_chain_last(const float* __restrict__ Bmat,
                                                       const float* __restrict__ Pin,
                                                       __bf16* __restrict__ Ptk) {
    __shared__ float sA[8][256];
    __shared__ float ws[4][8][256];
    const int t = threadIdx.x, j = t & 255, q = t >> 8, b = blockIdx.x;
    const int i0 = b * 8;  // k-range [i0, i0+8)
    float acc[8];
    sA[2 * q][j]     = Pin[(i0 + 2 * q) * 256 + j];
    sA[2 * q + 1][j] = Pin[(i0 + 2 * q + 1) * 256 + j];
    __syncthreads();
    chain_core(sA, Bmat, j, q, acc);
#pragma unroll
    for (int r = 0; r < 8; ++r) ws[q][r][j] = acc[r];
    __syncthreads();
#pragma unroll
    for (int d = 0; d < 2; ++d) {
        const int r = 2 * q + d;
        const float v = ws[0][r][j] + ws[1][r][j] + ws[2][r][j] + ws[3][r][j];
        sA[r][j] += v;  // own slots (rows 2q,2q+1, col j) -> no hazard
    }
    __syncthreads();
    // thread t -> col c = t>>2, sub = t&3; writes k = i0+sub*2, i0+sub*2+1 as one 4B store
    const int c = t >> 2, sub = t & 3;
    union { __bf16 h[2]; unsigned u; } pk;
    pk.h[0] = (__bf16)sA[sub * 2][c];
    pk.h[1] = (__bf16)sA[sub * 2 + 1][c];
    *(unsigned*)((void*)&Ptk[(size_t)(i0 >> 5) * 8192 + c * 32 + (i0 & 31) + sub * 2]) = pk.u;
}

// ---------------- big GEMM: y[65536][256] = x[65536][512] @ P ----------------
// Grid 1024 x 512 thr (8 waves = 2M x 4N). Block: 64 rows x 256 cols; wave: 32 x 64.
// xs[64][512] f32 (128 KB): staged ONCE, 2 instrs/row, each a contiguous 1KB half-row
// (within-row XOR chunk permutation: LDS 16B-slot s of row r holds global chunk s^(r&7);
// stays inside the same 128B line -> still 8 full-line txns; ds_reads 2-way-free).
// B: direct global from k-major Ptk; per (wave,nt,ks) load = part of a contiguous 1KB
// region (16 cols x 64B tile) -> fully coalesced. Depth-2 register prefetch, no barriers.
__global__ __launch_bounds__(512, 2) void nsm_gemm_xP(const float* __restrict__ x,
                                                      const __bf16* __restrict__ Ptk,
                                                      float* __restrict__ y) {
    __shared__ float xs[64][512];  // 128 KB
    const int tid = threadIdx.x;
    const int wave = tid >> 6, lane = tid & 63;
    const int l15 = lane & 15, lhi = lane >> 4;
    const int wm = wave >> 2, wn = wave & 3;
    const int m0 = blockIdx.x * 64;

    // ---- stage A once: 128 instrs (16/wave), each 1KB contiguous
#pragma unroll
    for (int i = 0; i < 16; ++i) {
        const int idx = wave * 16 + i;  // 0..127
        const int r = idx >> 1;         // row 0..63
        const int h = idx & 1;          // half of the 2KB row
        const float* src = x + (size_t)(m0 + r) * IN + h * 256 + ((lane ^ (r & 7)) << 2);
        GLOAD_LDS16(src, &xs[r][h * 256]);
    }

    f32x4 acc[2][4];
#pragma unroll
    for (int a = 0; a < 2; ++a)
#pragma unroll
        for (int c = 0; c < 4; ++c) acc[a][c] = (f32x4){0.f, 0.f, 0.f, 0.f};

    const __bf16* bPtr = Ptk + (size_t)(wn * 64 + l15) * 32 + lhi * 8;

    __syncthreads();  // xs ready

    // prologue: fragments for ks=0
    bf16x8 acur[2], bcur[4];
#pragma unroll
    for (int nt = 0; nt < 4; ++nt) bcur[nt] = *(const bf16x8*)(bPtr + nt * 512);
#pragma unroll
    for (int mt = 0; mt < 2; ++mt) {
        const int row = wm * 32 + mt * 16 + l15;
        const int c0 = (2 * lhi) ^ (row & 7);
        const f32x4 f0 = *(const f32x4*)&xs[row][c0 * 4];
        const f32x4 f1 = *(const f32x4*)&xs[row][(c0 ^ 1) * 4];
        bf16x8 tt;
        tt[0] = (__bf16)f0[0]; tt[1] = (__bf16)f0[1]; tt[2] = (__bf16)f0[2]; tt[3] = (__bf16)f0[3];
        tt[4] = (__bf16)f1[0]; tt[5] = (__bf16)f1[1]; tt[6] = (__bf16)f1[2]; tt[7] = (__bf16)f1[3];
        acur[mt] = tt;
    }

#pragma unroll
    for (int ks = 0; ks < 16; ++ks) {
        bf16x8 bnxt[4];
        f32x4 fn0[2], fn1[2];
        if (ks < 15) {
            // issue next-iteration loads before this iteration's MFMAs
#pragma unroll
            for (int nt = 0; nt < 4; ++nt)
                bnxt[nt] = *(const bf16x8*)(bPtr + (size_t)(ks + 1) * 8192 + nt * 512);
#pragma unroll
            for (int mt = 0; mt < 2; ++mt) {
                const int row = wm * 32 + mt * 16 + l15;
                const int c0 = (8 * (ks + 1) + 2 * lhi) ^ (row & 7);
                fn0[mt] = *(const f32x4*)&xs[row][c0 * 4];
                fn1[mt] = *(const f32x4*)&xs[row][(c0 ^ 1) * 4];
            }
        }
#pragma unroll
        for (int mt = 0; mt < 2; ++mt)
#pragma unroll
            for (int nt = 0; nt < 4; ++nt)
                acc[mt][nt] = __builtin_amdgcn_mfma_f32_16x16x32_bf16(acur[mt], bcur[nt], acc[mt][nt], 0, 0, 0);
        if (ks < 15) {
#pragma unroll
            for (int mt = 0; mt < 2; ++mt) {
                bf16x8 tt;
                tt[0] = (__bf16)fn0[mt][0]; tt[1] = (__bf16)fn0[mt][1];
                tt[2] = (__bf16)fn0[mt][2]; tt[3] = (__bf16)fn0[mt][3];
                tt[4] = (__bf16)fn1[mt][0]; tt[5] = (__bf16)fn1[mt][1];
                tt[6] = (__bf16)fn1[mt][2]; tt[7] = (__bf16)fn1[mt][3];
                acur[mt] = tt;
            }
#pragma unroll
            for (int nt = 0; nt < 4; ++nt) bcur[nt] = bnxt[nt];
        }
    }

#pragma unroll
    for (int mt = 0; mt < 2; ++mt) {
#pragma unroll
        for (int nt = 0; nt < 4; ++nt) {
            const int col = wn * 64 + nt * 16 + l15;
            const int row = m0 + wm * 32 + mt * 16 + lhi * 4;
#pragma unroll
            for (int r = 0; r < 4; ++r) y[(size_t)(row + r) * OUT + col] = acc[mt][nt][r];
        }
    }
}

extern "C" void kernel_launch(void* const* d_in, const int* in_sizes, int n_in,
                              void* d_out, int out_size, void* d_ws, size_t ws_size,
                              hipStream_t stream) {
    const float* x = (const float*)d_in[0];   // [65536][512]
    const float* W = (const float*)d_in[1];   // [256][512]
    const float* M = (const float*)d_in[2];   // [256][256]
    float* y = (float*)d_out;                 // [65536][256]

    char* ws = (char*)d_ws;
    float* Ta = (float*)(ws);                   // 256 KB
    float* Tb = (float*)(ws + (256 << 10));     // 256 KB
    float* Pa = (float*)(ws + (512 << 10));     // 512 KB
    float* Pb = (float*)(ws + (1024 << 10));    // 512 KB
    __bf16* Ptk = (__bf16*)(ws + (1536 << 10)); // 256 KB  bf16 k-major [16][256][32]

    // chain: P = W^T * prod_{i=0..4} (I + A^(2^i)), A = -M  (sum_{k=0}^{31} A^k)
    nsm_chain_step<<<96, 1024, 0, stream>>>(M, W, Ta, Pa, 1);   // Ta=A^2,  Pa=P0=W^T(I+A)
    nsm_chain_step<<<96, 1024, 0, stream>>>(Ta, Pa, Tb, Pb, 0); // Tb=A^4,  Pb=P1=P0(I+A^2)
    nsm_chain_step<<<96, 1024, 0, stream>>>(Tb, Pb, Ta, Pa, 0); // Ta=A^8,  Pa=P2=P1(I+A^4)
    nsm_chain_step<<<96, 1024, 0, stream>>>(Ta, Pa, Tb, Pb, 0); // Tb=A^16, Pb=P3=P2(I+A^8)
    nsm_chain_last<<<64, 1024, 0, stream>>>(Tb, Pb, Ptk);       // Ptk = bf16(P3(I+A^16)) k-major
    nsm_gemm_xP<<<BATCH / 64, 512, 0, stream>>>(x, Ptk, y);     // y = x @ P
}

// Round 8
// 84.930 us; speedup vs baseline: 1.1597x; 1.1597x over previous
//
#include <hip/hip_runtime.h>
#include <hip/hip_bf16.h>

// y = x @ (W^T * S), S = sum_{k=0}^{100} (-M)^k ~= prod_{i=0}^{4} (I + A^(2^i)), A = -M.
// Chain: 5 k-parallel launches; last writes P k-major bf16 Ptk[kt][col][32] (verified R7).
// GEMM: 1-WAVE WORKGROUPS, zero barriers. Each wave owns a 32x64 output tile and a
// private 3-deep LDS ring (24 KB): per 32-k tile it issues 8 x 1KB global_load_lds
// (A 4 + B 4), waits s_waitcnt vmcnt(8) (tile ready, next tile stays in flight),
// stages tile k+2, computes tile k. Steady in-flight = 16 KB/wave x 6 waves/CU ~ 96 KB
// -> latency-independent BW (the R1-R7 wall was in-flight-bytes/latency, not HBM).

typedef float f32x4 __attribute__((ext_vector_type(4)));
typedef __bf16 bf16x8 __attribute__((ext_vector_type(8)));

#define IN 512
#define OUT 256
#define BATCH 65536

#define GLOAD_LDS16(gp, lp)                                                              \
    __builtin_amdgcn_global_load_lds((const __attribute__((address_space(1))) void*)(gp), \
                                     (__attribute__((address_space(3))) void*)(lp), 16, 0, 0)

// ---------------- chain: k-parallel small matmuls (verified rounds 1-7) ----------------
__device__ __forceinline__ void chain_core(const float (*sA)[256], const float* __restrict__ B,
                                           int j, int q, float acc[8]) {
#pragma unroll
    for (int r = 0; r < 8; ++r) acc[r] = 0.f;
    const int kbase = q * 64;
#pragma unroll
    for (int it = 0; it < 16; ++it) {
        const int k = kbase + it * 4;
        const float b0 = B[(k + 0) * 256 + j];
        const float b1 = B[(k + 1) * 256 + j];
        const float b2 = B[(k + 2) * 256 + j];
        const float b3 = B[(k + 3) * 256 + j];
#pragma unroll
        for (int r = 0; r < 8; ++r) {
            const f32x4 av = *(const f32x4*)&sA[r][k];
            acc[r] += av[0] * b0 + av[1] * b1 + av[2] * b2 + av[3] * b3;
        }
    }
}

__global__ __launch_bounds__(1024) void nsm_chain_step(const float* __restrict__ Bmat,
                                                       const float* __restrict__ Pin,
                                                       float* __restrict__ Tout,
                                                       float* __restrict__ Pout,
                                                       const int first) {
    __shared__ float sA[8][256];
    __shared__ float ws[4][8][256];
    const int t = threadIdx.x, j = t & 255, q = t >> 8, b = blockIdx.x;
    float acc[8];
    const bool isT = (b < 32);
    if (isT) {
        const int i0 = b * 8;
        sA[2 * q][j]     = Bmat[(i0 + 2 * q) * 256 + j];
        sA[2 * q + 1][j] = Bmat[(i0 + 2 * q + 1) * 256 + j];
    } else {
        const int i0 = (b - 32) * 8;
        if (first) {
            sA[2 * q][j]     = Pin[j * IN + i0 + 2 * q];
            sA[2 * q + 1][j] = Pin[j * IN + i0 + 2 * q + 1];
        } else {
            sA[2 * q][j]     = Pin[(i0 + 2 * q) * 256 + j];
            sA[2 * q + 1][j] = Pin[(i0 + 2 * q + 1) * 256 + j];
        }
    }
    __syncthreads();
    chain_core(sA, Bmat, j, q, acc);
#pragma unroll
    for (int r = 0; r < 8; ++r) ws[q][r][j] = acc[r];
    __syncthreads();
#pragma unroll
    for (int d = 0; d < 2; ++d) {
        const int r = 2 * q + d;
        const float v = ws[0][r][j] + ws[1][r][j] + ws[2][r][j] + ws[3][r][j];
        if (isT) {
            const int i0 = b * 8;
            Tout[(i0 + r) * 256 + j] = v;
        } else {
            const int i0 = (b - 32) * 8;
            Pout[(i0 + r) * 256 + j] = first ? (sA[r][j] - v) : (sA[r][j] + v);
        }
    }
}

// grid 64: P_final = Pin + Pin*Bmat, written K-MAJOR bf16: Ptk[kt][col][kk] (verified R7).
__global__ __launch_bounds__(1024) void nsm_chain_last(const float* __restrict__ Bmat,
                                                       const float* __restrict__ Pin,
                                                       __bf16* __restrict__ Ptk) {
    __shared__ float sA[8][256];
    __shared__ float ws[4][8][256];
    const int t = threadIdx.x, j = t & 255, q = t >> 8, b = blockIdx.x;
    const int i0 = b * 8;  // k-range [i0, i0+8)
    float acc[8];
    sA[2 * q][j]     = Pin[(i0 + 2 * q) * 256 + j];
    sA[2 * q + 1][j] = Pin[(i0 + 2 * q + 1) * 256 + j];
    __syncthreads();
    chain_core(sA, Bmat, j, q, acc);
#pragma unroll
    for (int r = 0; r < 8; ++r) ws[q][r][j] = acc[r];
    __syncthreads();
#pragma unroll
    for (int d = 0; d < 2; ++d) {
        const int r = 2 * q + d;
        const float v = ws[0][r][j] + ws[1][r][j] + ws[2][r][j] + ws[3][r][j];
        sA[r][j] += v;
    }
    __syncthreads();
    const int c = t >> 2, sub = t & 3;
    union { __bf16 h[2]; unsigned u; } pk;
    pk.h[0] = (__bf16)sA[sub * 2][c];
    pk.h[1] = (__bf16)sA[sub * 2 + 1][c];
    *(unsigned*)((void*)&Ptk[(size_t)(i0 >> 5) * 8192 + c * 32 + (i0 & 31) + sub * 2]) = pk.u;
}

// ---------------- big GEMM: y[65536][256] = x[65536][512] @ P ----------------
// Grid 8192 x 64 thr (1 wave). Mapping: xcd-chunked so the 4 n-chunks of an x-stripe
// run on the same XCD (L2 reuse of x). Wave tile: 32 rows x 64 cols, 2x4 MFMA 16x16x32.
// LDS ring: xs[3][32][32] f32 (12 KB) + ps[3][64][32] bf16 (12 KB) = 24 KB -> 6 waves/CU.
// Per tile: A = 4 x 1KB gload_lds (8 rows, chunk XOR (row&7)); B = 4 x 1KB fully
// contiguous from k-major Ptk (16 cols x 64B, chunk XOR (col&3)).
__global__ __launch_bounds__(64, 2) void nsm_gemm_xP(const float* __restrict__ x,
                                                     const __bf16* __restrict__ Ptk,
                                                     float* __restrict__ y) {
    __shared__ float xs[3][32][32];    // 3 x 4 KB
    __shared__ __bf16 ps[3][64][32];   // 3 x 4 KB
    const int lane = threadIdx.x;
    const int l15 = lane & 15, lhi = lane >> 4;

    const unsigned g = blockIdx.x;
    const int xcd = g & 7;
    const int slot = g >> 3;            // 0..1023
    const int stripe = xcd * 256 + (slot >> 2);  // 0..2047
    const int nch = slot & 3;
    const int m0 = stripe * 32;
    const int n0 = nch * 64;

    auto stage = [&](int buf, int kt) {
        const int kk = kt * 32;
        // A: rows [0,32) in 4 ops; lane -> row r0+(lane>>3), chunk (lane&7)^(row&7)
#pragma unroll
        for (int i = 0; i < 4; ++i) {
            const int r0 = i * 8;
            const int row = r0 + (lane >> 3);
            const int gch = (lane & 7) ^ (row & 7);
            const float* src = x + (size_t)(m0 + row) * IN + kk + gch * 4;
            GLOAD_LDS16(src, &xs[buf][r0][0]);
        }
        // B: local cols [0,64) in 4 ops; lane -> col c0+(lane>>2), chunk (lane&3)^(col&3)
#pragma unroll
        for (int i = 0; i < 4; ++i) {
            const int c0 = i * 16;
            const int col = c0 + (lane >> 2);
            const int gch = (lane & 3) ^ (col & 3);
            const __bf16* src = Ptk + (size_t)kt * 8192 + (n0 + col) * 32 + gch * 8;
            GLOAD_LDS16(src, &ps[buf][c0][0]);
        }
    };

    f32x4 acc[2][4];
#pragma unroll
    for (int a = 0; a < 2; ++a)
#pragma unroll
        for (int c = 0; c < 4; ++c) acc[a][c] = (f32x4){0.f, 0.f, 0.f, 0.f};

    auto compute = [&](int buf) {
        bf16x8 bfr[4];
#pragma unroll
        for (int nt = 0; nt < 4; ++nt) {
            const int col = nt * 16 + l15;
            const int cs = lhi ^ (col & 3);
            bfr[nt] = *(const bf16x8*)&ps[buf][col][cs * 8];
        }
        bf16x8 af[2];
#pragma unroll
        for (int mt = 0; mt < 2; ++mt) {
            const int row = mt * 16 + l15;
            const int c0 = (2 * lhi) ^ (row & 7);
            const int c1 = (2 * lhi + 1) ^ (row & 7);
            const f32x4 f0 = *(const f32x4*)&xs[buf][row][c0 * 4];
            const f32x4 f1 = *(const f32x4*)&xs[buf][row][c1 * 4];
            bf16x8 t;
            t[0] = (__bf16)f0[0]; t[1] = (__bf16)f0[1]; t[2] = (__bf16)f0[2]; t[3] = (__bf16)f0[3];
            t[4] = (__bf16)f1[0]; t[5] = (__bf16)f1[1]; t[6] = (__bf16)f1[2]; t[7] = (__bf16)f1[3];
            af[mt] = t;
        }
#pragma unroll
        for (int mt = 0; mt < 2; ++mt)
#pragma unroll
            for (int nt = 0; nt < 4; ++nt)
                acc[mt][nt] = __builtin_amdgcn_mfma_f32_16x16x32_bf16(af[mt], bfr[nt], acc[mt][nt], 0, 0, 0);
    };

    stage(0, 0);
    stage(1, 1);
#pragma unroll
    for (int k = 0; k < 16; ++k) {
        if (k < 15) {
            asm volatile("s_waitcnt vmcnt(8)" ::: "memory");  // tile k landed; k+1 in flight
        } else {
            asm volatile("s_waitcnt vmcnt(0)" ::: "memory");
        }
        __builtin_amdgcn_sched_barrier(0);  // keep ds_reads below the wait
        if (k < 14) stage((k + 2) % 3, k + 2);
        compute(k % 3);
    }

#pragma unroll
    for (int mt = 0; mt < 2; ++mt) {
#pragma unroll
        for (int nt = 0; nt < 4; ++nt) {
            const int col = n0 + nt * 16 + l15;
            const int row = m0 + mt * 16 + lhi * 4;
#pragma unroll
            for (int r = 0; r < 4; ++r) y[(size_t)(row + r) * OUT + col] = acc[mt][nt][r];
        }
    }
}

extern "C" void kernel_launch(void* const* d_in, const int* in_sizes, int n_in,
                              void* d_out, int out_size, void* d_ws, size_t ws_size,
                              hipStream_t stream) {
    const float* x = (const float*)d_in[0];   // [65536][512]
    const float* W = (const float*)d_in[1];   // [256][512]
    const float* M = (const float*)d_in[2];   // [256][256]
    float* y = (float*)d_out;                 // [65536][256]

    char* ws = (char*)d_ws;
    float* Ta = (float*)(ws);                   // 256 KB
    float* Tb = (float*)(ws + (256 << 10));     // 256 KB
    float* Pa = (float*)(ws + (512 << 10));     // 512 KB
    float* Pb = (float*)(ws + (1024 << 10));    // 512 KB
    __bf16* Ptk = (__bf16*)(ws + (1536 << 10)); // 256 KB  bf16 k-major [16][256][32]

    // chain: P = W^T * prod_{i=0..4} (I + A^(2^i)), A = -M  (sum_{k=0}^{31} A^k)
    nsm_chain_step<<<96, 1024, 0, stream>>>(M, W, Ta, Pa, 1);   // Ta=A^2,  Pa=P0=W^T(I+A)
    nsm_chain_step<<<96, 1024, 0, stream>>>(Ta, Pa, Tb, Pb, 0); // Tb=A^4,  Pb=P1=P0(I+A^2)
    nsm_chain_step<<<96, 1024, 0, stream>>>(Tb, Pb, Ta, Pa, 0); // Ta=A^8,  Pa=P2=P1(I+A^4)
    nsm_chain_step<<<96, 1024, 0, stream>>>(Ta, Pa, Tb, Pb, 0); // Tb=A^16, Pb=P3=P2(I+A^8)
    nsm_chain_last<<<64, 1024, 0, stream>>>(Tb, Pb, Ptk);       // Ptk = bf16(P3(I+A^16)) k-major
    nsm_gemm_xP<<<8192, 64, 0, stream>>>(x, Ptk, y);            // y = x @ P
}

// Round 9
// 71.797 us; speedup vs baseline: 1.3718x; 1.1829x over previous
//
#include <hip/hip_runtime.h>
#include <hip/hip_bf16.h>

// y = x @ (W^T * S), S = sum_{k=0}^{100} (-M)^k ~= prod_{i=0}^{4} (I + A^(2^i)), A = -M.
// Chain: 5 k-parallel launches; last writes P k-major bf16 Ptk[kt][col][32] (verified R7/R8).
// GEMM: MINIMAL-BYTES design. Block tile 256x256 (grid 256 = exactly 1 block/CU):
// x staged ONCE total (134 MB), B staged once per block (67 MB) -> 201 MB staged total
// (the minimum). Ring-3 LDS (144 KB) + R6's counted-vmcnt schedule: 6 gload_lds per
// wave per tile, steady wait = s_waitcnt vmcnt(6) -> each tile has 2 full steps of
// flight time; loads never drain to 0 in the loop.

typedef float f32x4 __attribute__((ext_vector_type(4)));
typedef __bf16 bf16x8 __attribute__((ext_vector_type(8)));

#define IN 512
#define OUT 256
#define BATCH 65536

#define GLOAD_LDS16(gp, lp)                                                              \
    __builtin_amdgcn_global_load_lds((const __attribute__((address_space(1))) void*)(gp), \
                                     (__attribute__((address_space(3))) void*)(lp), 16, 0, 0)

// ---------------- chain: k-parallel small matmuls (verified rounds 1-8) ----------------
__device__ __forceinline__ void chain_core(const float (*sA)[256], const float* __restrict__ B,
                                           int j, int q, float acc[8]) {
#pragma unroll
    for (int r = 0; r < 8; ++r) acc[r] = 0.f;
    const int kbase = q * 64;
#pragma unroll
    for (int it = 0; it < 16; ++it) {
        const int k = kbase + it * 4;
        const float b0 = B[(k + 0) * 256 + j];
        const float b1 = B[(k + 1) * 256 + j];
        const float b2 = B[(k + 2) * 256 + j];
        const float b3 = B[(k + 3) * 256 + j];
#pragma unroll
        for (int r = 0; r < 8; ++r) {
            const f32x4 av = *(const f32x4*)&sA[r][k];
            acc[r] += av[0] * b0 + av[1] * b1 + av[2] * b2 + av[3] * b3;
        }
    }
}

__global__ __launch_bounds__(1024) void nsm_chain_step(const float* __restrict__ Bmat,
                                                       const float* __restrict__ Pin,
                                                       float* __restrict__ Tout,
                                                       float* __restrict__ Pout,
                                                       const int first) {
    __shared__ float sA[8][256];
    __shared__ float ws[4][8][256];
    const int t = threadIdx.x, j = t & 255, q = t >> 8, b = blockIdx.x;
    float acc[8];
    const bool isT = (b < 32);
    if (isT) {
        const int i0 = b * 8;
        sA[2 * q][j]     = Bmat[(i0 + 2 * q) * 256 + j];
        sA[2 * q + 1][j] = Bmat[(i0 + 2 * q + 1) * 256 + j];
    } else {
        const int i0 = (b - 32) * 8;
        if (first) {
            sA[2 * q][j]     = Pin[j * IN + i0 + 2 * q];
            sA[2 * q + 1][j] = Pin[j * IN + i0 + 2 * q + 1];
        } else {
            sA[2 * q][j]     = Pin[(i0 + 2 * q) * 256 + j];
            sA[2 * q + 1][j] = Pin[(i0 + 2 * q + 1) * 256 + j];
        }
    }
    __syncthreads();
    chain_core(sA, Bmat, j, q, acc);
#pragma unroll
    for (int r = 0; r < 8; ++r) ws[q][r][j] = acc[r];
    __syncthreads();
#pragma unroll
    for (int d = 0; d < 2; ++d) {
        const int r = 2 * q + d;
        const float v = ws[0][r][j] + ws[1][r][j] + ws[2][r][j] + ws[3][r][j];
        if (isT) {
            const int i0 = b * 8;
            Tout[(i0 + r) * 256 + j] = v;
        } else {
            const int i0 = (b - 32) * 8;
            Pout[(i0 + r) * 256 + j] = first ? (sA[r][j] - v) : (sA[r][j] + v);
        }
    }
}

// grid 64: P_final = Pin + Pin*Bmat, written K-MAJOR bf16: Ptk[kt][col][kk] (verified R7/R8).
__global__ __launch_bounds__(1024) void nsm_chain_last(const float* __restrict__ Bmat,
                                                       const float* __restrict__ Pin,
                                                       __bf16* __restrict__ Ptk) {
    __shared__ float sA[8][256];
    __shared__ float ws[4][8][256];
    const int t = threadIdx.x, j = t & 255, q = t >> 8, b = blockIdx.x;
    const int i0 = b * 8;  // k-range [i0, i0+8)
    float acc[8];
    sA[2 * q][j]     = Pin[(i0 + 2 * q) * 256 + j];
    sA[2 * q + 1][j] = Pin[(i0 + 2 * q + 1) * 256 + j];
    __syncthreads();
    chain_core(sA, Bmat, j, q, acc);
#pragma unroll
    for (int r = 0; r < 8; ++r) ws[q][r][j] = acc[r];
    __syncthreads();
#pragma unroll
    for (int d = 0; d < 2; ++d) {
        const int r = 2 * q + d;
        const float v = ws[0][r][j] + ws[1][r][j] + ws[2][r][j] + ws[3][r][j];
        sA[r][j] += v;
    }
    __syncthreads();
    const int c = t >> 2, sub = t & 3;
    union { __bf16 h[2]; unsigned u; } pk;
    pk.h[0] = (__bf16)sA[sub * 2][c];
    pk.h[1] = (__bf16)sA[sub * 2 + 1][c];
    *(unsigned*)((void*)&Ptk[(size_t)(i0 >> 5) * 8192 + c * 32 + (i0 & 31) + sub * 2]) = pk.u;
}

// ---------------- big GEMM: y[65536][256] = x[65536][512] @ P ----------------
// Grid 256 x 512 thr (8 waves = 4M x 2N). Block: 256 rows x ALL 256 cols -> x staged
// once globally, B once per block (201 MB total staged). Wave tile 64 x 128 (4mt x 8nt,
// acc 128 VGPR). Ring-3 LDS 144 KB (1 block/CU): per 32-k tile A 32 KB (32 ops) +
// B 16 KB (16 ops) = 6 gload_lds per wave. Steady wait vmcnt(6): tile k ready, tile
// k+1 (6 ops) stays in flight; stage k+2 after the barrier.
__global__ __launch_bounds__(512, 2) void nsm_gemm_xP(const float* __restrict__ x,
                                                      const __bf16* __restrict__ Ptk,
                                                      float* __restrict__ y) {
    __shared__ float xs[3][256][32];    // 3 x 32 KB
    __shared__ __bf16 ps[3][256][32];   // 3 x 16 KB
    const int tid = threadIdx.x;
    const int wave = tid >> 6, lane = tid & 63;
    const int l15 = lane & 15, lhi = lane >> 4;
    const int wm = wave >> 1, wn = wave & 1;  // 4M x 2N
    const int m0 = blockIdx.x * 256;

    auto stage = [&](int buf, int kt) {
        const int kk = kt * 32;
        // A: wave stages rows [32w, 32w+32) in 4 ops (8 rows x 128B each, contiguous 1KB)
#pragma unroll
        for (int i = 0; i < 4; ++i) {
            const int r0 = wave * 32 + i * 8;
            const int row = r0 + (lane >> 3);
            const int gch = (lane & 7) ^ (row & 7);
            const float* src = x + (size_t)(m0 + row) * IN + kk + gch * 4;
            GLOAD_LDS16(src, &xs[buf][r0][0]);
        }
        // B: wave stages cols [32w, 32w+32) in 2 ops (16 cols x 64B each, contiguous 1KB)
#pragma unroll
        for (int i = 0; i < 2; ++i) {
            const int c0 = wave * 32 + i * 16;
            const int col = c0 + (lane >> 2);
            const int gch = (lane & 3) ^ (col & 3);
            const __bf16* src = Ptk + (size_t)kt * 8192 + col * 32 + gch * 8;
            GLOAD_LDS16(src, &ps[buf][c0][0]);
        }
    };

    f32x4 acc[4][8];
#pragma unroll
    for (int a = 0; a < 4; ++a)
#pragma unroll
        for (int c = 0; c < 8; ++c) acc[a][c] = (f32x4){0.f, 0.f, 0.f, 0.f};

    auto compute = [&](int buf) {
        bf16x8 bfr[8];
#pragma unroll
        for (int nt = 0; nt < 8; ++nt) {
            const int col = wn * 128 + nt * 16 + l15;
            const int cs = lhi ^ (col & 3);
            bfr[nt] = *(const bf16x8*)&ps[buf][col][cs * 8];
        }
        bf16x8 af[4];
#pragma unroll
        for (int mt = 0; mt < 4; ++mt) {
            const int row = wm * 64 + mt * 16 + l15;
            const int c0 = (2 * lhi) ^ (row & 7);
            const int c1 = (2 * lhi + 1) ^ (row & 7);
            const f32x4 f0 = *(const f32x4*)&xs[buf][row][c0 * 4];
            const f32x4 f1 = *(const f32x4*)&xs[buf][row][c1 * 4];
            bf16x8 t;
            t[0] = (__bf16)f0[0]; t[1] = (__bf16)f0[1]; t[2] = (__bf16)f0[2]; t[3] = (__bf16)f0[3];
            t[4] = (__bf16)f1[0]; t[5] = (__bf16)f1[1]; t[6] = (__bf16)f1[2]; t[7] = (__bf16)f1[3];
            af[mt] = t;
        }
#pragma unroll
        for (int mt = 0; mt < 4; ++mt)
#pragma unroll
            for (int nt = 0; nt < 8; ++nt)
                acc[mt][nt] = __builtin_amdgcn_mfma_f32_16x16x32_bf16(af[mt], bfr[nt], acc[mt][nt], 0, 0, 0);
    };

    stage(0, 0);
    stage(1, 1);
#pragma unroll
    for (int k = 0; k < 16; ++k) {
        if (k < 15) {
            asm volatile("s_waitcnt vmcnt(6)" ::: "memory");  // tile k landed; k+1 in flight
        } else {
            asm volatile("s_waitcnt vmcnt(0)" ::: "memory");
        }
        __builtin_amdgcn_s_barrier();
        __builtin_amdgcn_sched_barrier(0);  // keep ds_reads below the wait/barrier
        if (k < 14) stage((k + 2) % 3, k + 2);
        compute(k % 3);
    }

#pragma unroll
    for (int mt = 0; mt < 4; ++mt) {
#pragma unroll
        for (int nt = 0; nt < 8; ++nt) {
            const int col = wn * 128 + nt * 16 + l15;
            const int row = m0 + wm * 64 + mt * 16 + lhi * 4;
#pragma unroll
            for (int r = 0; r < 4; ++r) y[(size_t)(row + r) * OUT + col] = acc[mt][nt][r];
        }
    }
}

extern "C" void kernel_launch(void* const* d_in, const int* in_sizes, int n_in,
                              void* d_out, int out_size, void* d_ws, size_t ws_size,
                              hipStream_t stream) {
    const float* x = (const float*)d_in[0];   // [65536][512]
    const float* W = (const float*)d_in[1];   // [256][512]
    const float* M = (const float*)d_in[2];   // [256][256]
    float* y = (float*)d_out;                 // [65536][256]

    char* ws = (char*)d_ws;
    float* Ta = (float*)(ws);                   // 256 KB
    float* Tb = (float*)(ws + (256 << 10));     // 256 KB
    float* Pa = (float*)(ws + (512 << 10));     // 512 KB
    float* Pb = (float*)(ws + (1024 << 10));    // 512 KB
    __bf16* Ptk = (__bf16*)(ws + (1536 << 10)); // 256 KB  bf16 k-major [16][256][32]

    // chain: P = W^T * prod_{i=0..4} (I + A^(2^i)), A = -M  (sum_{k=0}^{31} A^k)
    nsm_chain_step<<<96, 1024, 0, stream>>>(M, W, Ta, Pa, 1);   // Ta=A^2,  Pa=P0=W^T(I+A)
    nsm_chain_step<<<96, 1024, 0, stream>>>(Ta, Pa, Tb, Pb, 0); // Tb=A^4,  Pb=P1=P0(I+A^2)
    nsm_chain_step<<<96, 1024, 0, stream>>>(Tb, Pb, Ta, Pa, 0); // Ta=A^8,  Pa=P2=P1(I+A^4)
    nsm_chain_step<<<96, 1024, 0, stream>>>(Ta, Pa, Tb, Pb, 0); // Tb=A^16, Pb=P3=P2(I+A^8)
    nsm_chain_last<<<64, 1024, 0, stream>>>(Tb, Pb, Ptk);       // Ptk = bf16(P3(I+A^16)) k-major
    nsm_gemm_xP<<<256, 512, 0, stream>>>(x, Ptk, y);            // y = x @ P
}

// Round 10
// 66.986 us; speedup vs baseline: 1.4703x; 1.0718x over previous
//
#include <hip/hip_runtime.h>
#include <hip/hip_bf16.h>

// y = x @ (W^T * S), S = sum_{k=0}^{100} (-M)^k ~= prod_{i=0}^{3} (I + A^(2^i)), A = -M
// (16 terms; truncation ~ rho^16 ~ 1.5e-5 relative -- far below bf16 rounding; R4's
// accidental rho^8-level error only moved absmax 0.031->0.047).
// Chain: 4 k-parallel launches; last writes P k-major bf16 Ptk[kt][col][32] (verified R7-R9).
// GEMM: R8's barrier-free 1-wave-block structure (measured 14.4 TB/s aggregate staging)
// at the VGPR-feasible byte-minimal wave tile 64x128 (537 MB staged vs R8's 1050 MB).
// Private ring-2 LDS (32 KB), 16 gload_lds per 32-k tile, steady s_waitcnt vmcnt(16),
// ZERO s_barrier. 5 blocks/CU (LDS-capped), 32 KB/wave continuously in flight.

typedef float f32x4 __attribute__((ext_vector_type(4)));
typedef __bf16 bf16x8 __attribute__((ext_vector_type(8)));

#define IN 512
#define OUT 256
#define BATCH 65536

#define GLOAD_LDS16(gp, lp)                                                              \
    __builtin_amdgcn_global_load_lds((const __attribute__((address_space(1))) void*)(gp), \
                                     (__attribute__((address_space(3))) void*)(lp), 16, 0, 0)

// ---------------- chain: k-parallel small matmuls (verified rounds 1-9) ----------------
__device__ __forceinline__ void chain_core(const float (*sA)[256], const float* __restrict__ B,
                                           int j, int q, float acc[8]) {
#pragma unroll
    for (int r = 0; r < 8; ++r) acc[r] = 0.f;
    const int kbase = q * 64;
#pragma unroll
    for (int it = 0; it < 16; ++it) {
        const int k = kbase + it * 4;
        const float b0 = B[(k + 0) * 256 + j];
        const float b1 = B[(k + 1) * 256 + j];
        const float b2 = B[(k + 2) * 256 + j];
        const float b3 = B[(k + 3) * 256 + j];
#pragma unroll
        for (int r = 0; r < 8; ++r) {
            const f32x4 av = *(const f32x4*)&sA[r][k];
            acc[r] += av[0] * b0 + av[1] * b1 + av[2] * b2 + av[3] * b3;
        }
    }
}

__global__ __launch_bounds__(1024) void nsm_chain_step(const float* __restrict__ Bmat,
                                                       const float* __restrict__ Pin,
                                                       float* __restrict__ Tout,
                                                       float* __restrict__ Pout,
                                                       const int first) {
    __shared__ float sA[8][256];
    __shared__ float ws[4][8][256];
    const int t = threadIdx.x, j = t & 255, q = t >> 8, b = blockIdx.x;
    float acc[8];
    const bool isT = (b < 32);
    if (isT) {
        const int i0 = b * 8;
        sA[2 * q][j]     = Bmat[(i0 + 2 * q) * 256 + j];
        sA[2 * q + 1][j] = Bmat[(i0 + 2 * q + 1) * 256 + j];
    } else {
        const int i0 = (b - 32) * 8;
        if (first) {
            sA[2 * q][j]     = Pin[j * IN + i0 + 2 * q];
            sA[2 * q + 1][j] = Pin[j * IN + i0 + 2 * q + 1];
        } else {
            sA[2 * q][j]     = Pin[(i0 + 2 * q) * 256 + j];
            sA[2 * q + 1][j] = Pin[(i0 + 2 * q + 1) * 256 + j];
        }
    }
    __syncthreads();
    chain_core(sA, Bmat, j, q, acc);
#pragma unroll
    for (int r = 0; r < 8; ++r) ws[q][r][j] = acc[r];
    __syncthreads();
#pragma unroll
    for (int d = 0; d < 2; ++d) {
        const int r = 2 * q + d;
        const float v = ws[0][r][j] + ws[1][r][j] + ws[2][r][j] + ws[3][r][j];
        if (isT) {
            const int i0 = b * 8;
            Tout[(i0 + r) * 256 + j] = v;
        } else {
            const int i0 = (b - 32) * 8;
            Pout[(i0 + r) * 256 + j] = first ? (sA[r][j] - v) : (sA[r][j] + v);
        }
    }
}

// grid 64: P_final = Pin + Pin*Bmat, written K-MAJOR bf16: Ptk[kt][col][kk] (verified R7-R9).
__global__ __launch_bounds__(1024) void nsm_chain_last(const float* __restrict__ Bmat,
                                                       const float* __restrict__ Pin,
                                                       __bf16* __restrict__ Ptk) {
    __shared__ float sA[8][256];
    __shared__ float ws[4][8][256];
    const int t = threadIdx.x, j = t & 255, q = t >> 8, b = blockIdx.x;
    const int i0 = b * 8;  // k-range [i0, i0+8)
    float acc[8];
    sA[2 * q][j]     = Pin[(i0 + 2 * q) * 256 + j];
    sA[2 * q + 1][j] = Pin[(i0 + 2 * q + 1) * 256 + j];
    __syncthreads();
    chain_core(sA, Bmat, j, q, acc);
#pragma unroll
    for (int r = 0; r < 8; ++r) ws[q][r][j] = acc[r];
    __syncthreads();
#pragma unroll
    for (int d = 0; d < 2; ++d) {
        const int r = 2 * q + d;
        const float v = ws[0][r][j] + ws[1][r][j] + ws[2][r][j] + ws[3][r][j];
        sA[r][j] += v;
    }
    __syncthreads();
    const int c = t >> 2, sub = t & 3;
    union { __bf16 h[2]; unsigned u; } pk;
    pk.h[0] = (__bf16)sA[sub * 2][c];
    pk.h[1] = (__bf16)sA[sub * 2 + 1][c];
    *(unsigned*)((void*)&Ptk[(size_t)(i0 >> 5) * 8192 + c * 32 + (i0 & 31) + sub * 2]) = pk.u;
}

// ---------------- big GEMM: y[65536][256] = x[65536][512] @ P ----------------
// Grid 2048 x 64 thr (1 wave). bid -> (xcd = bid&7, w = bid>>3): stripe = xcd*128 + (w>>1),
// n-half = w&1 -> the two halves of an x-stripe are adjacent on the SAME XCD (L2 x reuse).
// Wave tile 64 x 128 (4mt x 8nt, acc 128 VGPR). Private ring-2: xs[2][64][32] f32 (16 KB)
// + ps[2][128][32] bf16 (8 KB) = 32 KB -> 5 blocks/CU. Per 32-k tile: A 8 + B 8 = 16
// gload_lds (each 1 KB contiguous). Steady wait vmcnt(16): tile k landed, tile k+1's 16
// ops stay in flight; stage(k+2) issued after lgkmcnt(0) (frag reads done -> ring-2 safe).
// NO s_barrier anywhere: waves self-stagger, in-flight never drains.
__global__ __launch_bounds__(64, 2) void nsm_gemm_xP(const float* __restrict__ x,
                                                     const __bf16* __restrict__ Ptk,
                                                     float* __restrict__ y) {
    __shared__ float xs[2][64][32];    // 2 x 8 KB
    __shared__ __bf16 ps[2][128][32];  // 2 x 8 KB
    const int lane = threadIdx.x;
    const int l15 = lane & 15, lhi = lane >> 4;

    const unsigned bid = blockIdx.x;
    const int xcd = bid & 7;
    const int w = bid >> 3;                    // 0..255
    const int stripe = xcd * 128 + (w >> 1);   // 0..1023
    const int nh = w & 1;
    const int m0 = stripe * 64;
    const int n0 = nh * 128;

    auto stage = [&](int buf, int kt) {
        const int kk = kt * 32;
        // A: 64 rows in 8 ops (8 rows x 128B each, 1KB contiguous; chunk XOR (row&7))
#pragma unroll
        for (int i = 0; i < 8; ++i) {
            const int r0 = i * 8;
            const int row = r0 + (lane >> 3);
            const int gch = (lane & 7) ^ (row & 7);
            GLOAD_LDS16(x + (size_t)(m0 + row) * IN + kk + gch * 4, &xs[buf][r0][0]);
        }
        // B: 128 local cols in 8 ops (16 cols x 64B each, 1KB contiguous; chunk XOR (col&3))
#pragma unroll
        for (int i = 0; i < 8; ++i) {
            const int c0 = i * 16;
            const int col = c0 + (lane >> 2);
            const int gch = (lane & 3) ^ (col & 3);
            GLOAD_LDS16(Ptk + (size_t)kt * 8192 + (n0 + col) * 32 + gch * 8, &ps[buf][c0][0]);
        }
    };

    f32x4 acc[4][8];
#pragma unroll
    for (int a = 0; a < 4; ++a)
#pragma unroll
        for (int c = 0; c < 8; ++c) acc[a][c] = (f32x4){0.f, 0.f, 0.f, 0.f};

    stage(0, 0);
    stage(1, 1);

#pragma unroll
    for (int k = 0; k < 16; ++k) {
        if (k < 15) {
            asm volatile("s_waitcnt vmcnt(16)" ::: "memory");  // tile k landed; k+1 in flight
        } else {
            asm volatile("s_waitcnt vmcnt(0)" ::: "memory");
        }
        __builtin_amdgcn_sched_barrier(0);

        const int buf = k & 1;  // static after full unroll
        bf16x8 bfr[8];
#pragma unroll
        for (int nt = 0; nt < 8; ++nt) {
            const int col = nt * 16 + l15;
            const int cs = lhi ^ (col & 3);
            bfr[nt] = *(const bf16x8*)&ps[buf][col][cs * 8];
        }
        bf16x8 af[4];
#pragma unroll
        for (int mt = 0; mt < 4; ++mt) {
            const int row = mt * 16 + l15;
            const int c0 = (2 * lhi) ^ (row & 7);
            const f32x4 f0 = *(const f32x4*)&xs[buf][row][c0 * 4];
            const f32x4 f1 = *(const f32x4*)&xs[buf][row][(c0 ^ 1) * 4];
            bf16x8 t;
            t[0] = (__bf16)f0[0]; t[1] = (__bf16)f0[1]; t[2] = (__bf16)f0[2]; t[3] = (__bf16)f0[3];
            t[4] = (__bf16)f1[0]; t[5] = (__bf16)f1[1]; t[6] = (__bf16)f1[2]; t[7] = (__bf16)f1[3];
            af[mt] = t;
        }
        asm volatile("s_waitcnt lgkmcnt(0)" ::: "memory");  // frag reads in regs
        __builtin_amdgcn_sched_barrier(0);
        if (k < 14) stage(buf, k + 2);  // overwrite this tile's buffers (reads are done)

#pragma unroll
        for (int mt = 0; mt < 4; ++mt)
#pragma unroll
            for (int nt = 0; nt < 8; ++nt)
                acc[mt][nt] = __builtin_amdgcn_mfma_f32_16x16x32_bf16(af[mt], bfr[nt], acc[mt][nt], 0, 0, 0);
    }

#pragma unroll
    for (int mt = 0; mt < 4; ++mt) {
#pragma unroll
        for (int nt = 0; nt < 8; ++nt) {
            const int col = n0 + nt * 16 + l15;
            const int row = m0 + mt * 16 + lhi * 4;
#pragma unroll
            for (int r = 0; r < 4; ++r) y[(size_t)(row + r) * OUT + col] = acc[mt][nt][r];
        }
    }
}

extern "C" void kernel_launch(void* const* d_in, const int* in_sizes, int n_in,
                              void* d_out, int out_size, void* d_ws, size_t ws_size,
                              hipStream_t stream) {
    const float* x = (const float*)d_in[0];   // [65536][512]
    const float* W = (const float*)d_in[1];   // [256][512]
    const float* M = (const float*)d_in[2];   // [256][256]
    float* y = (float*)d_out;                 // [65536][256]

    char* ws = (char*)d_ws;
    float* Ta = (float*)(ws);                   // 256 KB
    float* Tb = (float*)(ws + (256 << 10));     // 256 KB
    float* Pa = (float*)(ws + (512 << 10));     // 512 KB
    float* Pb = (float*)(ws + (1024 << 10));    // 512 KB
    __bf16* Ptk = (__bf16*)(ws + (1536 << 10)); // 256 KB  bf16 k-major [16][256][32]

    // chain: P = W^T * prod_{i=0..3} (I + A^(2^i)), A = -M  (sum_{k=0}^{15} A^k)
    nsm_chain_step<<<96, 1024, 0, stream>>>(M, W, Ta, Pa, 1);   // Ta=A^2, Pa=P0=W^T(I+A)
    nsm_chain_step<<<96, 1024, 0, stream>>>(Ta, Pa, Tb, Pb, 0); // Tb=A^4, Pb=P1=P0(I+A^2)
    nsm_chain_step<<<96, 1024, 0, stream>>>(Tb, Pb, Ta, Pa, 0); // Ta=A^8, Pa=P2=P1(I+A^4)
    nsm_chain_last<<<64, 1024, 0, stream>>>(Ta, Pa, Ptk);       // Ptk = bf16((P2(I+A^8))^T)
    nsm_gemm_xP<<<2048, 64, 0, stream>>>(x, Ptk, y);            // y = x @ P
}

// Round 12
// 66.681 us; speedup vs baseline: 1.4771x; 1.0046x over previous
//
#include <hip/hip_runtime.h>
#include <hip/hip_bf16.h>

// y = x @ (W^T * S), S = sum_{k=0}^{100} (-M)^k ~= prod_{i=0}^{3} (I + A^(2^i)), A = -M
// (16 terms; truncation ~rho^16 ~1.5e-5 relative, far below bf16 rounding).
// Chain: 4 k-parallel launches; last writes P k-major bf16 Ptk[kt][col][32] (verified R7-R10).
// GEMM: R10's barrier-free 1-wave-block pipeline, residency-fixed. LDS = A-ring only
// (16 KB); B-fragments load straight to registers via PINNED inline-asm
// global_load_dwordx4 (coalesced 1KB/instr from k-major Ptk; volatile asm can't be
// compiler-sunk; counts in vmcnt). Offsets kept within the 13-bit signed imm range by
// using two base addresses 4096 B apart (R11 compile fix). VGPR ~230 -> 2 waves/SIMD
// = 8 waves/CU; grid 2048 = 8 blocks/CU -> all blocks resident, zero barriers.

typedef float f32x4 __attribute__((ext_vector_type(4)));
typedef __bf16 bf16x8 __attribute__((ext_vector_type(8)));

#define IN 512
#define OUT 256
#define BATCH 65536

#define GLOAD_LDS16(gp, lp)                                                              \
    __builtin_amdgcn_global_load_lds((const __attribute__((address_space(1))) void*)(gp), \
                                     (__attribute__((address_space(3))) void*)(lp), 16, 0, 0)

// ---------------- chain: k-parallel small matmuls (verified rounds 1-10) ----------------
__device__ __forceinline__ void chain_core(const float (*sA)[256], const float* __restrict__ B,
                                           int j, int q, float acc[8]) {
#pragma unroll
    for (int r = 0; r < 8; ++r) acc[r] = 0.f;
    const int kbase = q * 64;
#pragma unroll
    for (int it = 0; it < 16; ++it) {
        const int k = kbase + it * 4;
        const float b0 = B[(k + 0) * 256 + j];
        const float b1 = B[(k + 1) * 256 + j];
        const float b2 = B[(k + 2) * 256 + j];
        const float b3 = B[(k + 3) * 256 + j];
#pragma unroll
        for (int r = 0; r < 8; ++r) {
            const f32x4 av = *(const f32x4*)&sA[r][k];
            acc[r] += av[0] * b0 + av[1] * b1 + av[2] * b2 + av[3] * b3;
        }
    }
}

__global__ __launch_bounds__(1024) void nsm_chain_step(const float* __restrict__ Bmat,
                                                       const float* __restrict__ Pin,
                                                       float* __restrict__ Tout,
                                                       float* __restrict__ Pout,
                                                       const int first) {
    __shared__ float sA[8][256];
    __shared__ float ws[4][8][256];
    const int t = threadIdx.x, j = t & 255, q = t >> 8, b = blockIdx.x;
    float acc[8];
    const bool isT = (b < 32);
    if (isT) {
        const int i0 = b * 8;
        sA[2 * q][j]     = Bmat[(i0 + 2 * q) * 256 + j];
        sA[2 * q + 1][j] = Bmat[(i0 + 2 * q + 1) * 256 + j];
    } else {
        const int i0 = (b - 32) * 8;
        if (first) {
            sA[2 * q][j]     = Pin[j * IN + i0 + 2 * q];
            sA[2 * q + 1][j] = Pin[j * IN + i0 + 2 * q + 1];
        } else {
            sA[2 * q][j]     = Pin[(i0 + 2 * q) * 256 + j];
            sA[2 * q + 1][j] = Pin[(i0 + 2 * q + 1) * 256 + j];
        }
    }
    __syncthreads();
    chain_core(sA, Bmat, j, q, acc);
#pragma unroll
    for (int r = 0; r < 8; ++r) ws[q][r][j] = acc[r];
    __syncthreads();
#pragma unroll
    for (int d = 0; d < 2; ++d) {
        const int r = 2 * q + d;
        const float v = ws[0][r][j] + ws[1][r][j] + ws[2][r][j] + ws[3][r][j];
        if (isT) {
            const int i0 = b * 8;
            Tout[(i0 + r) * 256 + j] = v;
        } else {
            const int i0 = (b - 32) * 8;
            Pout[(i0 + r) * 256 + j] = first ? (sA[r][j] - v) : (sA[r][j] + v);
        }
    }
}

// grid 64: P_final = Pin + Pin*Bmat, written K-MAJOR bf16: Ptk[kt][col][kk] (verified R7-R10).
__global__ __launch_bounds__(1024) void nsm_chain_last(const float* __restrict__ Bmat,
                                                       const float* __restrict__ Pin,
                                                       __bf16* __restrict__ Ptk) {
    __shared__ float sA[8][256];
    __shared__ float ws[4][8][256];
    const int t = threadIdx.x, j = t & 255, q = t >> 8, b = blockIdx.x;
    const int i0 = b * 8;  // k-range [i0, i0+8)
    float acc[8];
    sA[2 * q][j]     = Pin[(i0 + 2 * q) * 256 + j];
    sA[2 * q + 1][j] = Pin[(i0 + 2 * q + 1) * 256 + j];
    __syncthreads();
    chain_core(sA, Bmat, j, q, acc);
#pragma unroll
    for (int r = 0; r < 8; ++r) ws[q][r][j] = acc[r];
    __syncthreads();
#pragma unroll
    for (int d = 0; d < 2; ++d) {
        const int r = 2 * q + d;
        const float v = ws[0][r][j] + ws[1][r][j] + ws[2][r][j] + ws[3][r][j];
        sA[r][j] += v;
    }
    __syncthreads();
    const int c = t >> 2, sub = t & 3;
    union { __bf16 h[2]; unsigned u; } pk;
    pk.h[0] = (__bf16)sA[sub * 2][c];
    pk.h[1] = (__bf16)sA[sub * 2 + 1][c];
    *(unsigned*)((void*)&Ptk[(size_t)(i0 >> 5) * 8192 + c * 32 + (i0 & 31) + sub * 2]) = pk.u;
}

// ---------------- big GEMM: y[65536][256] = x[65536][512] @ P ----------------
// Grid 2048 x 64 thr (1 wave). bid -> (xcd = bid&7, w = bid>>3): the two n-halves of an
// x-stripe are adjacent on the SAME XCD (L2 x reuse). Wave tile 64x128 (4mt x 8nt).
// A: private LDS ring-2 xs[2][64][32] f32 (16 KB), 8 gload_lds per tile (1 KB each,
//    chunk XOR (row&7) swizzle). B: NO LDS -- 8 pinned asm global_load_dwordx4 per tile
//    into alternating register sets (each instr = 16 cols x 64 B = 1 KB contiguous of
//    k-major Ptk, L2-resident); two base addrs 4 KB apart keep imm offsets <= 3072.
// 16 vm-ops/tile; steady s_waitcnt vmcnt(16); no s_barrier anywhere.
__global__ __launch_bounds__(64, 2) void nsm_gemm_xP(const float* __restrict__ x,
                                                     const __bf16* __restrict__ Ptk,
                                                     float* __restrict__ y) {
    __shared__ float xs[2][64][32];  // 2 x 8 KB
    const int lane = threadIdx.x;
    const int l15 = lane & 15, lhi = lane >> 4;

    const unsigned bid = blockIdx.x;
    const int xcd = bid & 7;
    const int w = bid >> 3;                    // 0..255
    const int stripe = xcd * 128 + (w >> 1);   // 0..1023
    const int nh = w & 1;
    const int m0 = stripe * 64;
    const int n0 = nh * 128;

    auto stageA = [&](int buf, int kt) {
        const int kk = kt * 32;
#pragma unroll
        for (int i = 0; i < 8; ++i) {
            const int r0 = i * 8;
            const int row = r0 + (lane >> 3);
            const int gch = (lane & 7) ^ (row & 7);
            GLOAD_LDS16(x + (size_t)(m0 + row) * IN + kk + gch * 4, &xs[buf][r0][0]);
        }
    };

    // per-lane B address: col = n0 + nt*16 + l15 (stride 64 B), k-chunk lhi (16 B);
    // tile stride 16384 B. Lane pattern per instr = contiguous 1 KB.
    unsigned long long baddr = (unsigned long long)(const void*)Ptk +
                               (unsigned long long)(n0 * 64 + l15 * 64 + lhi * 16);
    bf16x8 b0[8], b1[8];

#define LOADB(SET)                                                                        \
    do {                                                                                  \
        const unsigned long long baddr2 = baddr + 4096;                                   \
        _Pragma("unroll")                                                                 \
        for (int nt = 0; nt < 8; ++nt)                                                    \
            asm volatile("global_load_dwordx4 %0, %1, off offset:%2"                      \
                         : "=v"(SET[nt])                                                  \
                         : "v"(nt < 4 ? baddr : baddr2), "n"((nt & 3) * 1024));           \
        baddr += 16384;                                                                   \
    } while (0)

    f32x4 acc[4][8];
#pragma unroll
    for (int a = 0; a < 4; ++a)
#pragma unroll
        for (int c = 0; c < 8; ++c) acc[a][c] = (f32x4){0.f, 0.f, 0.f, 0.f};

    // prologue: tiles 0 and 1 (A then B each; FIFO order matches vmcnt counting)
    stageA(0, 0);
    LOADB(b0);
    stageA(1, 1);
    LOADB(b1);

#pragma unroll
    for (int k = 0; k < 16; ++k) {
        if (k < 15) {
            asm volatile("s_waitcnt vmcnt(16)" ::: "memory");  // tile k landed; k+1 in flight
        } else {
            asm volatile("s_waitcnt vmcnt(0)" ::: "memory");
        }
        __builtin_amdgcn_sched_barrier(0);

        const int buf = k & 1;  // static after full unroll
        // A fragments from LDS (swizzled)
        f32x4 f0[4], f1[4];
#pragma unroll
        for (int mt = 0; mt < 4; ++mt) {
            const int row = mt * 16 + l15;
            const int c0 = (2 * lhi) ^ (row & 7);
            f0[mt] = *(const f32x4*)&xs[buf][row][c0 * 4];
            f1[mt] = *(const f32x4*)&xs[buf][row][(c0 ^ 1) * 4];
        }
        asm volatile("s_waitcnt lgkmcnt(0)" ::: "memory");  // frag reads in regs
        __builtin_amdgcn_sched_barrier(0);
        if (k < 14) stageA(buf, k + 2);  // ring-2 overwrite is now safe

        bf16x8 af[4];
#pragma unroll
        for (int mt = 0; mt < 4; ++mt) {
            bf16x8 t;
            t[0] = (__bf16)f0[mt][0]; t[1] = (__bf16)f0[mt][1];
            t[2] = (__bf16)f0[mt][2]; t[3] = (__bf16)f0[mt][3];
            t[4] = (__bf16)f1[mt][0]; t[5] = (__bf16)f1[mt][1];
            t[6] = (__bf16)f1[mt][2]; t[7] = (__bf16)f1[mt][3];
            af[mt] = t;
        }

        if ((k & 1) == 0) {
#pragma unroll
            for (int mt = 0; mt < 4; ++mt)
#pragma unroll
                for (int nt = 0; nt < 8; ++nt)
                    acc[mt][nt] = __builtin_amdgcn_mfma_f32_16x16x32_bf16(af[mt], b0[nt], acc[mt][nt], 0, 0, 0);
            if (k < 14) LOADB(b0);  // reload this set for tile k+2 (operands already consumed)
        } else {
#pragma unroll
            for (int mt = 0; mt < 4; ++mt)
#pragma unroll
                for (int nt = 0; nt < 8; ++nt)
                    acc[mt][nt] = __builtin_amdgcn_mfma_f32_16x16x32_bf16(af[mt], b1[nt], acc[mt][nt], 0, 0, 0);
            if (k < 14) LOADB(b1);
        }
    }
#undef LOADB

#pragma unroll
    for (int mt = 0; mt < 4; ++mt) {
#pragma unroll
        for (int nt = 0; nt < 8; ++nt) {
            const int col = n0 + nt * 16 + l15;
            const int row = m0 + mt * 16 + lhi * 4;
#pragma unroll
            for (int r = 0; r < 4; ++r) y[(size_t)(row + r) * OUT + col] = acc[mt][nt][r];
        }
    }
}

extern "C" void kernel_launch(void* const* d_in, const int* in_sizes, int n_in,
                              void* d_out, int out_size, void* d_ws, size_t ws_size,
                              hipStream_t stream) {
    const float* x = (const float*)d_in[0];   // [65536][512]
    const float* W = (const float*)d_in[1];   // [256][512]
    const float* M = (const float*)d_in[2];   // [256][256]
    float* y = (float*)d_out;                 // [65536][256]

    char* ws = (char*)d_ws;
    float* Ta = (float*)(ws);                   // 256 KB
    float* Tb = (float*)(ws + (256 << 10));     // 256 KB
    float* Pa = (float*)(ws + (512 << 10));     // 512 KB
    float* Pb = (float*)(ws + (1024 << 10));    // 512 KB
    __bf16* Ptk = (__bf16*)(ws + (1536 << 10)); // 256 KB  bf16 k-major [16][256][32]

    // chain: P = W^T * prod_{i=0..3} (I + A^(2^i)), A = -M  (sum_{k=0}^{15} A^k)
    nsm_chain_step<<<96, 1024, 0, stream>>>(M, W, Ta, Pa, 1);   // Ta=A^2, Pa=P0=W^T(I+A)
    nsm_chain_step<<<96, 1024, 0, stream>>>(Ta, Pa, Tb, Pb, 0); // Tb=A^4, Pb=P1=P0(I+A^2)
    nsm_chain_step<<<96, 1024, 0, stream>>>(Tb, Pb, Ta, Pa, 0); // Ta=A^8, Pa=P2=P1(I+A^4)
    nsm_chain_last<<<64, 1024, 0, stream>>>(Ta, Pa, Ptk);       // Ptk = bf16((P2(I+A^8))^T)
    nsm_gemm_xP<<<2048, 64, 0, stream>>>(x, Ptk, y);            // y = x @ P
}